// Round 3
// baseline (4238.385 us; speedup 1.0000x reference)
//
#include <hip/hip_runtime.h>
#include <hip/hip_bf16.h>

#define Bb 512
#define Tt 128
#define Nn 256
#define Mm 128
#define Ss 128   // = T
#define Gg 512   // 4M
#define Kk 384   // N + M

typedef __bf16 bf16_t;
typedef __bf16 bf16x8 __attribute__((ext_vector_type(8)));
typedef float f32x4 __attribute__((ext_vector_type(4)));

__device__ __forceinline__ float fast_tanh(float x) {
  x = fminf(15.f, fmaxf(-15.f, x));
  float e = __expf(2.f * x);
  return 1.f - 2.f * __builtin_amdgcn_rcpf(e + 1.f);
}
__device__ __forceinline__ float fast_sigmoid(float x) {
  return __builtin_amdgcn_rcpf(1.f + __expf(-x));
}

// ---------------- prep: pack [W_ih | W_hh] rows in block-permuted order, bf16 ----
// perm: r = mt*64 + type*16 + ml  ->  g = type*128 + mt*16 + ml
__global__ void prep_kernel(const float* __restrict__ W_ih, const float* __restrict__ W_hh,
                            const float* __restrict__ b_ih, const float* __restrict__ b_hh,
                            bf16_t* __restrict__ Wp, float* __restrict__ bp) {
  int r = blockIdx.x;          // 0..511
  int k = threadIdx.x;         // 0..383
  int mt = r >> 6, l = r & 63, type = l >> 4, ml = l & 15;
  int g = type * 128 + mt * 16 + ml;
  float w = (k < 256) ? W_ih[g * 256 + k] : W_hh[g * 128 + (k - 256)];
  Wp[r * 384 + k] = (bf16_t)w;
  if (k == 0) bp[r] = b_ih[g] + b_hh[g];
}

// ---------------- feat_proj: fp[b][s][n] = sum_t X[b][t][n] * W_x[s][t] ---------
// block = (b, s-chunk of 32); thread = n; W read as wave-uniform scalar (SGPR) loads.
__global__ __launch_bounds__(256) void featproj_kernel(
    const float* __restrict__ X, const float* __restrict__ W_e, float* __restrict__ fp) {
  int b  = blockIdx.x >> 2;
  int s0 = (blockIdx.x & 3) << 5;
  int tid = threadIdx.x;
  __shared__ float Xs[32][256];
  float acc[32];
#pragma unroll
  for (int i = 0; i < 32; ++i) acc[i] = 0.f;
  for (int tc = 0; tc < 4; ++tc) {
    __syncthreads();
#pragma unroll
    for (int i = 0; i < 32; ++i)
      Xs[i][tid] = X[((size_t)b * Tt + tc * 32 + i) * Nn + tid];
    __syncthreads();
    for (int tt = 0; tt < 32; ++tt) {
      float xv = Xs[tt][tid];
#pragma unroll
      for (int ss = 0; ss < 32; ++ss)
        acc[ss] = fmaf(W_e[(s0 + ss) * 384 + 256 + tc * 32 + tt], xv, acc[ss]);
    }
  }
#pragma unroll
  for (int ss = 0; ss < 32; ++ss)
    fp[((size_t)b * Ss + s0 + ss) * Nn + tid] = acc[ss];
}

// ---------------- per-step attention: a_proj + tanh/E + softmax + x_tilde -------
// grid = B blocks (one per b), 256 threads (thread = n).
__global__ __launch_bounds__(256) void attn_kernel(
    const float* __restrict__ X, const float* __restrict__ W_e, const float* __restrict__ v_e,
    const float* __restrict__ fp, const float* __restrict__ h, const float* __restrict__ c,
    bf16_t* __restrict__ Axt, int t) {
  int b = blockIdx.x;
  int tid = threadIdx.x;
  __shared__ float hs[256];
  __shared__ float a_s[128];
  __shared__ float vv[128];
  __shared__ float redm[4], reds[4];
  hs[tid] = (tid < 128) ? h[b * Mm + tid] : c[b * Mm + (tid - 128)];
  if (tid < 128) vv[tid] = v_e[tid];
  __syncthreads();
  if (tid < 128) {
    const float4* wrow = (const float4*)(W_e + tid * 384);  // W_hs row s=tid
    const float4* hv = (const float4*)hs;
    float acc = 0.f;
#pragma unroll 8
    for (int j = 0; j < 64; ++j) {
      float4 w = wrow[j]; float4 hh = hv[j];
      acc += w.x * hh.x + w.y * hh.y + w.z * hh.z + w.w * hh.w;
    }
    a_s[tid] = acc;
  }
  __syncthreads();
  const float* fpb = fp + (size_t)b * Ss * Nn + tid;
  float E = 0.f;
#pragma unroll 4
  for (int s = 0; s < Ss; ++s) {
    float f = fpb[(size_t)s * Nn];
    E = fmaf(vv[s], fast_tanh(a_s[s] + f), E);
  }
  // softmax over n (block of 256)
  float m = E;
#pragma unroll
  for (int off = 32; off > 0; off >>= 1) m = fmaxf(m, __shfl_xor(m, off, 64));
  if ((tid & 63) == 0) redm[tid >> 6] = m;
  __syncthreads();
  m = fmaxf(fmaxf(redm[0], redm[1]), fmaxf(redm[2], redm[3]));
  float p = __expf(E - m);
  float sum = p;
#pragma unroll
  for (int off = 32; off > 0; off >>= 1) sum += __shfl_xor(sum, off, 64);
  if ((tid & 63) == 0) reds[tid >> 6] = sum;
  __syncthreads();
  sum = reds[0] + reds[1] + reds[2] + reds[3];
  float alpha = p * __builtin_amdgcn_rcpf(sum);
  float xv = X[((size_t)b * Tt + t) * Nn + tid];
  Axt[(size_t)b * Kk + tid] = (bf16_t)(xv * alpha);
}

// ---------------- per-step gates GEMM (bf16 MFMA) + fused LSTM update ----------
// grid = 64 blocks: (bt 0..7) x (mt 0..7); tile 64 b x 64 g-rows (i/f/g/o quads).
__global__ __launch_bounds__(256) void gates_kernel(
    const bf16_t* __restrict__ A, const bf16_t* __restrict__ Wp, const float* __restrict__ bp,
    float* __restrict__ h, float* __restrict__ c, bf16_t* __restrict__ Anext,
    float* __restrict__ out, int t) {
  int bt = blockIdx.x >> 3, mt = blockIdx.x & 7;
  int b0 = bt << 6;
  int r0 = mt << 6;
  int tid = threadIdx.x;
  __shared__ __align__(16) bf16_t As[64][392];
  __shared__ __align__(16) bf16_t Wsm[64][392];
  __shared__ float gl[64][66];
  for (int idx = tid; idx < 64 * 48; idx += 256) {
    int row = idx / 48, c8 = idx % 48;
    *(uint4*)&As[row][c8 * 8]  = *(const uint4*)&A [((size_t)(b0 + row)) * Kk + c8 * 8];
    *(uint4*)&Wsm[row][c8 * 8] = *(const uint4*)&Wp[((size_t)(r0 + row)) * Kk + c8 * 8];
  }
  __syncthreads();
  int w = tid >> 6, lane = tid & 63;
  int wr = (w >> 1) << 5, wc = (w & 1) << 5;  // wave b-offset, g-offset
  int fr = lane & 15, ksel = lane >> 4;
  f32x4 acc00{}, acc01{}, acc10{}, acc11{};
  for (int kk = 0; kk < 12; ++kk) {
    int kof = kk * 32 + ksel * 8;
    bf16x8 a0  = *(const bf16x8*)&As[wr + fr][kof];
    bf16x8 a1  = *(const bf16x8*)&As[wr + 16 + fr][kof];
    bf16x8 bf0 = *(const bf16x8*)&Wsm[wc + fr][kof];
    bf16x8 bf1 = *(const bf16x8*)&Wsm[wc + 16 + fr][kof];
    acc00 = __builtin_amdgcn_mfma_f32_16x16x32_bf16(a0, bf0, acc00, 0, 0, 0);
    acc01 = __builtin_amdgcn_mfma_f32_16x16x32_bf16(a0, bf1, acc01, 0, 0, 0);
    acc10 = __builtin_amdgcn_mfma_f32_16x16x32_bf16(a1, bf0, acc10, 0, 0, 0);
    acc11 = __builtin_amdgcn_mfma_f32_16x16x32_bf16(a1, bf1, acc11, 0, 0, 0);
  }
  // D layout: col = lane&15 (g), row = (lane>>4)*4 + reg (b)
  int drow = ksel * 4;
#pragma unroll
  for (int r = 0; r < 4; ++r) {
    gl[wr + drow + r][wc + fr]           = acc00[r];
    gl[wr + drow + r][wc + 16 + fr]      = acc01[r];
    gl[wr + 16 + drow + r][wc + fr]      = acc10[r];
    gl[wr + 16 + drow + r][wc + 16 + fr] = acc11[r];
  }
  __syncthreads();
  // LSTM update: 64 b x 16 m per block
  for (int idx = tid; idx < 1024; idx += 256) {
    int bl = idx >> 4, ml = idx & 15;
    int bg = b0 + bl, mg = mt * 16 + ml;
    float ig = fast_sigmoid(gl[bl][ 0 + ml] + bp[r0 +  0 + ml]);
    float fg = fast_sigmoid(gl[bl][16 + ml] + bp[r0 + 16 + ml]);
    float gg = fast_tanh   (gl[bl][32 + ml] + bp[r0 + 32 + ml]);
    float og = fast_sigmoid(gl[bl][48 + ml] + bp[r0 + 48 + ml]);
    float co = c[bg * Mm + mg];
    float c2 = fg * co + ig * gg;
    float h2 = og * fast_tanh(c2);
    c[bg * Mm + mg] = c2;
    h[bg * Mm + mg] = h2;
    Anext[(size_t)bg * Kk + Nn + mg] = (bf16_t)h2;
    out[((size_t)t * Bb + bg) * Mm + mg] = h2;
  }
}

extern "C" void kernel_launch(void* const* d_in, const int* in_sizes, int n_in,
                              void* d_out, int out_size, void* d_ws, size_t ws_size,
                              hipStream_t stream) {
  const float* X    = (const float*)d_in[0];
  const float* W_e  = (const float*)d_in[1];
  const float* v_e  = (const float*)d_in[2];
  const float* W_ih = (const float*)d_in[3];
  const float* W_hh = (const float*)d_in[4];
  const float* b_ih = (const float*)d_in[5];
  const float* b_hh = (const float*)d_in[6];
  float* out = (float*)d_out;

  char* ws = (char*)d_ws;
  float*  fp = (float*)ws;                       // 512*128*256*4 = 67108864
  float*  h  = (float*)(ws + 67108864);          // 262144
  float*  c  = (float*)(ws + 67371008);          // 262144
  bf16_t* A0 = (bf16_t*)(ws + 67633152);         // 393216
  bf16_t* A1 = (bf16_t*)(ws + 68026368);         // 393216
  bf16_t* Wp = (bf16_t*)(ws + 68419584);         // 393216
  float*  bp = (float*)(ws + 68812800);          // 2048

  hipMemsetAsync(h, 0, 262144, stream);
  hipMemsetAsync(c, 0, 262144, stream);
  hipMemsetAsync(A0, 0, 393216, stream);
  prep_kernel<<<512, 384, 0, stream>>>(W_ih, W_hh, b_ih, b_hh, Wp, bp);
  featproj_kernel<<<2048, 256, 0, stream>>>(X, W_e, fp);
  for (int t = 0; t < Tt; ++t) {
    bf16_t* Acur = (t & 1) ? A1 : A0;
    bf16_t* Anxt = (t & 1) ? A0 : A1;
    attn_kernel<<<Bb, 256, 0, stream>>>(X, W_e, v_e, fp, h, c, Acur, t);
    gates_kernel<<<64, 256, 0, stream>>>(Acur, Wp, bp, h, c, Anxt, out, t);
  }
}

// Round 4
// 1533.994 us; speedup vs baseline: 2.7630x; 2.7630x over previous
//
#include <hip/hip_runtime.h>
#include <hip/hip_bf16.h>

#define Bb 512
#define Tt 128
#define Nn 256
#define Mm 128

typedef __bf16 bf16_t;
typedef __bf16 bf16x8 __attribute__((ext_vector_type(8)));
typedef float f32x4 __attribute__((ext_vector_type(4)));

__device__ __forceinline__ float bflo(unsigned u) { return __uint_as_float(u << 16); }
__device__ __forceinline__ float bfhi(unsigned u) { return __uint_as_float(u & 0xffff0000u); }

__device__ __forceinline__ float fast_sigmoid(float x) {
  return __builtin_amdgcn_rcpf(1.f + __expf(-x));   // graceful at +-inf
}
__device__ __forceinline__ float fast_tanh(float x) {
  float e = __expf(2.f * x);
  return 1.f - 2.f * __builtin_amdgcn_rcpf(e + 1.f);
}

// ---- prep: Whs packed into MFMA B-frag order: [st(8)][kk(8)][lane(64)][8] ----
// value = W_e[s*384 + m], s = st*16 + (lane&15), m = kk*32 + (lane>>4)*8 + j
__global__ void prep_whs(const float* __restrict__ W_e, bf16_t* __restrict__ Whs_pk) {
  int blk = blockIdx.x;            // 0..63 = st*8 + kk
  int st = blk >> 3, kk = blk & 7;
  int lane = threadIdx.x;          // 0..63
  int s = st * 16 + (lane & 15);
  int m0 = kk * 32 + (lane >> 4) * 8;
  bf16_t v[8];
#pragma unroll
  for (int j = 0; j < 8; ++j) v[j] = (bf16_t)W_e[s * 384 + m0 + j];
  *(bf16x8*)(Whs_pk + ((size_t)blk * 64 + lane) * 8) = *(bf16x8*)v;
}

// ---- prep: Wp packed B-frags [gt(32)][kk(12)][lane(64)][8] + permuted bias ----
// perm row r = mt*64 + type*16 + ml  <->  g = type*128 + mt*16 + ml
__global__ void prep_wp(const float* __restrict__ W_ih, const float* __restrict__ W_hh,
                        const float* __restrict__ b_ih, const float* __restrict__ b_hh,
                        bf16_t* __restrict__ Wp_pk, float* __restrict__ bp) {
  int blk = blockIdx.x;            // 0..383 = gt*12 + kk
  int gt = blk / 12, kk = blk % 12;
  int lane = threadIdx.x;
  int r = gt * 16 + (lane & 15);
  int mt = r >> 6, type = (r >> 4) & 3, ml = r & 15;
  int g = type * 128 + mt * 16 + ml;
  int k0 = kk * 32 + (lane >> 4) * 8;
  bf16_t v[8];
#pragma unroll
  for (int j = 0; j < 8; ++j) {
    int k = k0 + j;
    float wv = (k < 256) ? W_ih[g * 256 + k] : W_hh[g * 128 + (k - 256)];
    v[j] = (bf16_t)wv;
  }
  *(bf16x8*)(Wp_pk + ((size_t)blk * 64 + lane) * 8) = *(bf16x8*)v;
  if (kk == 0 && lane < 16) bp[r] = b_ih[g] + b_hh[g];
}

// ---- featproj: F[b][s][n] = bf16( exp( 2 * sum_t X[b][t][n] * W_x[s][t] ) ) ----
__global__ __launch_bounds__(256) void featproj_kernel(
    const float* __restrict__ X, const float* __restrict__ W_e, bf16_t* __restrict__ F) {
  int b  = blockIdx.x >> 2;
  int s0 = (blockIdx.x & 3) << 5;
  int tid = threadIdx.x;
  __shared__ float Xs[32][256];
  float acc[32];
#pragma unroll
  for (int i = 0; i < 32; ++i) acc[i] = 0.f;
  for (int tc = 0; tc < 4; ++tc) {
    __syncthreads();
#pragma unroll
    for (int i = 0; i < 32; ++i)
      Xs[i][tid] = X[((size_t)b * Tt + tc * 32 + i) * Nn + tid];
    __syncthreads();
    for (int tt = 0; tt < 32; ++tt) {
      float xv = Xs[tt][tid];
#pragma unroll
      for (int ss = 0; ss < 32; ++ss)
        acc[ss] = fmaf(W_e[(s0 + ss) * 384 + 256 + tc * 32 + tt], xv, acc[ss]);
    }
  }
#pragma unroll
  for (int ss = 0; ss < 32; ++ss)
    F[((size_t)b * 128 + s0 + ss) * 256 + tid] = (bf16_t)__expf(2.f * acc[ss]);
}

// ---- fused recurrence: 256 blocks x 512 threads, block owns 2 b's for all t ----
__global__ __launch_bounds__(512, 2) void fused_kernel(
    const float* __restrict__ X, const bf16_t* __restrict__ F,
    const bf16_t* __restrict__ Whs_pk, const bf16_t* __restrict__ Wp_pk,
    const float* __restrict__ bp, const float* __restrict__ v_e,
    float* __restrict__ out) {
  __shared__ __align__(16) bf16_t WhsL[32768];     // 64 KB, loaded once
  __shared__ __align__(16) bf16_t hsA[16][264];    // A-frag [h|c] rows 0,1; pad->2-way
  __shared__ __align__(16) bf16_t xtA[16][392];    // A-frag [x~|h]  rows 0,1
  __shared__ float2 avL[2][128];                   // {exp(2a), -2v}
  __shared__ float  Ep[8][256];
  __shared__ float  gld[2][512];
  __shared__ float  hcC[2][128];                   // c state (f32)
  __shared__ float  vmL[128];
  __shared__ float  bpL[512];
  __shared__ float  red[8];

  int bid = blockIdx.x;
  int b0 = 2 * ((bid & 7) * 32 + (bid >> 3));      // XCD-contiguous b-ranges
  int tid = threadIdx.x;
  int w = tid >> 6, lane = tid & 63;
  int fr = lane & 15, ksel = lane >> 4;

  // one-time init
  for (int i = tid; i < 4096; i += 512) ((uint4*)WhsL)[i] = ((const uint4*)Whs_pk)[i];
  for (int i = tid; i < 16 * 264; i += 512) ((bf16_t*)hsA)[i] = (bf16_t)0.f;
  for (int i = tid; i < 16 * 392; i += 512) ((bf16_t*)xtA)[i] = (bf16_t)0.f;
  if (tid < 128) { vmL[tid] = -2.f * v_e[tid]; hcC[0][tid] = 0.f; hcC[1][tid] = 0.f; }
  bpL[tid] = bp[tid];
  __syncthreads();

  for (int t = 0; t < Tt; ++t) {
    // ---- phase 1: a[b][s] = hs @ Whs^T (MFMA); av = {exp(2a), -2v} ----
    {
      f32x4 pa{};
#pragma unroll
      for (int kk = 0; kk < 8; ++kk) {
        bf16x8 af = *(const bf16x8*)&hsA[fr][kk * 32 + ksel * 8];
        bf16x8 bf = *(const bf16x8*)&WhsL[((w * 8 + kk) * 64 + lane) * 8];
        pa = __builtin_amdgcn_mfma_f32_16x16x32_bf16(af, bf, pa, 0, 0, 0);
      }
      if (ksel == 0) {                       // D rows 0,1 = b0,b1 live in regs 0,1
        int s = w * 16 + fr;
        float vm = vmL[s];
        avL[0][s] = make_float2(__expf(2.f * pa[0]), vm);
        avL[1][s] = make_float2(__expf(2.f * pa[1]), vm);
      }
    }
    __syncthreads();

    // ---- phase 2: E partials. wave w: b = w>>2, s in [(w&3)*32, +32), n = 4*lane+j
    {
      int ab = w >> 2, s0 = (w & 3) * 32;
      const bf16_t* Fb = F + ((size_t)(b0 + ab) * 128 + s0) * 256 + 4 * lane;
      f32x4 En{};
#pragma unroll 8
      for (int s = 0; s < 32; ++s) {
        float2 avv = avL[ab][s0 + s];
        uint2 u = *(const uint2*)(Fb + (size_t)s * 256);
        float f0 = bflo(u.x), f1 = bfhi(u.x), f2 = bflo(u.y), f3 = bfhi(u.y);
        En[0] = fmaf(avv.y, __builtin_amdgcn_rcpf(fmaf(avv.x, f0, 1.f)), En[0]);
        En[1] = fmaf(avv.y, __builtin_amdgcn_rcpf(fmaf(avv.x, f1, 1.f)), En[1]);
        En[2] = fmaf(avv.y, __builtin_amdgcn_rcpf(fmaf(avv.x, f2, 1.f)), En[2]);
        En[3] = fmaf(avv.y, __builtin_amdgcn_rcpf(fmaf(avv.x, f3, 1.f)), En[3]);
      }
      *(f32x4*)&Ep[w][4 * lane] = En;
    }
    __syncthreads();

    // ---- phase 3: softmax over n + x_tilde (threads: sb = tid>>8, sn = tid&255)
    {
      int sb = tid >> 8, sn = tid & 255;
      float E = Ep[sb * 4 + 0][sn] + Ep[sb * 4 + 1][sn] +
                Ep[sb * 4 + 2][sn] + Ep[sb * 4 + 3][sn];
      float mx = E;
#pragma unroll
      for (int off = 32; off; off >>= 1) mx = fmaxf(mx, __shfl_xor(mx, off, 64));
      if (lane == 0) red[tid >> 6] = mx;
      __syncthreads();
      mx = fmaxf(fmaxf(red[sb * 4 + 0], red[sb * 4 + 1]),
                 fmaxf(red[sb * 4 + 2], red[sb * 4 + 3]));
      float p = __expf(E - mx);
      float sm = p;
#pragma unroll
      for (int off = 32; off; off >>= 1) sm += __shfl_xor(sm, off, 64);
      __syncthreads();
      if (lane == 0) red[tid >> 6] = sm;
      __syncthreads();
      sm = red[sb * 4 + 0] + red[sb * 4 + 1] + red[sb * 4 + 2] + red[sb * 4 + 3];
      float alpha = p * __builtin_amdgcn_rcpf(sm);
      float xv = X[((size_t)(b0 + sb) * Tt + t) * Nn + sn];
      xtA[sb][sn] = (bf16_t)(xv * alpha);
    }
    __syncthreads();

    // ---- phase 4: gates = [x~|h] @ Wp^T (MFMA), wave w owns g-tiles 4w..4w+3 ----
    {
      f32x4 acg[4] = {f32x4{}, f32x4{}, f32x4{}, f32x4{}};
      const bf16_t* wpw = Wp_pk + (size_t)(4 * w) * 6144 + (size_t)lane * 8;
#pragma unroll
      for (int kk = 0; kk < 12; ++kk) {
        bf16x8 af = *(const bf16x8*)&xtA[fr][kk * 32 + ksel * 8];
#pragma unroll
        for (int j = 0; j < 4; ++j) {
          bf16x8 bfg = *(const bf16x8*)(wpw + j * 6144 + kk * 512);
          acg[j] = __builtin_amdgcn_mfma_f32_16x16x32_bf16(af, bfg, acg[j], 0, 0, 0);
        }
      }
      if (ksel == 0) {
#pragma unroll
        for (int j = 0; j < 4; ++j) {
          gld[0][(4 * w + j) * 16 + fr] = acg[j][0];
          gld[1][(4 * w + j) * 16 + fr] = acg[j][1];
        }
      }
    }
    __syncthreads();

    // ---- phase 5: LSTM pointwise update (threads 0..255: ub = tid>>7, m = tid&127)
    if (tid < 256) {
      int ub = tid >> 7, m = tid & 127;
      int r = ((m >> 4) << 6) + (m & 15);
      float ig = fast_sigmoid(gld[ub][r]      + bpL[r]);
      float fg = fast_sigmoid(gld[ub][r + 16] + bpL[r + 16]);
      float gg = fast_tanh   (gld[ub][r + 32] + bpL[r + 32]);
      float og = fast_sigmoid(gld[ub][r + 48] + bpL[r + 48]);
      float c2 = fg * hcC[ub][m] + ig * gg;
      float h2 = og * fast_tanh(c2);
      hcC[ub][m] = c2;
      hsA[ub][m] = (bf16_t)h2;
      hsA[ub][128 + m] = (bf16_t)c2;
      xtA[ub][256 + m] = (bf16_t)h2;
      out[((size_t)t * Bb + (b0 + ub)) * Mm + m] = h2;
    }
    __syncthreads();
  }
}

extern "C" void kernel_launch(void* const* d_in, const int* in_sizes, int n_in,
                              void* d_out, int out_size, void* d_ws, size_t ws_size,
                              hipStream_t stream) {
  const float* X    = (const float*)d_in[0];
  const float* W_e  = (const float*)d_in[1];
  const float* v_e  = (const float*)d_in[2];
  const float* W_ih = (const float*)d_in[3];
  const float* W_hh = (const float*)d_in[4];
  const float* b_ih = (const float*)d_in[5];
  const float* b_hh = (const float*)d_in[6];
  float* out = (float*)d_out;

  char* ws = (char*)d_ws;
  bf16_t* F      = (bf16_t*)ws;                    // 512*128*256*2 = 33,554,432
  bf16_t* Whs_pk = (bf16_t*)(ws + 33554432);       // 65,536
  bf16_t* Wp_pk  = (bf16_t*)(ws + 33619968);       // 393,216
  float*  bp     = (float*) (ws + 34013184);       // 2,048

  prep_whs<<<64, 64, 0, stream>>>(W_e, Whs_pk);
  prep_wp<<<384, 64, 0, stream>>>(W_ih, W_hh, b_ih, b_hh, Wp_pk, bp);
  featproj_kernel<<<2048, 256, 0, stream>>>(X, W_e, F);
  fused_kernel<<<256, 512, 0, stream>>>(X, F, Whs_pk, Wp_pk, bp, v_e, out);
}

// Round 5
// 1494.113 us; speedup vs baseline: 2.8367x; 1.0267x over previous
//
#include <hip/hip_runtime.h>
#include <hip/hip_bf16.h>

#define Bb 512
#define Tt 128
#define Nn 256
#define Mm 128

typedef __bf16 bf16_t;
typedef __bf16 bf16x8 __attribute__((ext_vector_type(8)));
typedef float f32x4 __attribute__((ext_vector_type(4)));

__device__ __forceinline__ float bflo(unsigned u) { return __uint_as_float(u << 16); }
__device__ __forceinline__ float bfhi(unsigned u) { return __uint_as_float(u & 0xffff0000u); }

__device__ __forceinline__ float fast_sigmoid(float x) {
  return __builtin_amdgcn_rcpf(1.f + __expf(-x));   // graceful at +-inf
}
__device__ __forceinline__ float fast_tanh(float x) {
  float e = __expf(2.f * x);
  return 1.f - 2.f * __builtin_amdgcn_rcpf(e + 1.f);
}

// ---- prep: Whs packed into MFMA B-frag order: [st(8)][kk(8)][lane(64)][8] ----
// value = W_e[s*384 + m], s = st*16 + (lane&15), m = kk*32 + (lane>>4)*8 + j
__global__ void prep_whs(const float* __restrict__ W_e, bf16_t* __restrict__ Whs_pk) {
  int blk = blockIdx.x;            // 0..63 = st*8 + kk
  int st = blk >> 3, kk = blk & 7;
  int lane = threadIdx.x;          // 0..63
  int s = st * 16 + (lane & 15);
  int m0 = kk * 32 + (lane >> 4) * 8;
  bf16_t v[8];
#pragma unroll
  for (int j = 0; j < 8; ++j) v[j] = (bf16_t)W_e[s * 384 + m0 + j];
  *(bf16x8*)(Whs_pk + ((size_t)blk * 64 + lane) * 8) = *(bf16x8*)v;
}

// ---- prep: Wp packed B-frags [gt(32)][kk(12)][lane(64)][8] + permuted bias ----
// perm row r = mt*64 + type*16 + ml  <->  g = type*128 + mt*16 + ml
__global__ void prep_wp(const float* __restrict__ W_ih, const float* __restrict__ W_hh,
                        const float* __restrict__ b_ih, const float* __restrict__ b_hh,
                        bf16_t* __restrict__ Wp_pk, float* __restrict__ bp) {
  int blk = blockIdx.x;            // 0..383 = gt*12 + kk
  int gt = blk / 12, kk = blk % 12;
  int lane = threadIdx.x;
  int r = gt * 16 + (lane & 15);
  int mt = r >> 6, type = (r >> 4) & 3, ml = r & 15;
  int g = type * 128 + mt * 16 + ml;
  int k0 = kk * 32 + (lane >> 4) * 8;
  bf16_t v[8];
#pragma unroll
  for (int j = 0; j < 8; ++j) {
    int k = k0 + j;
    float wv = (k < 256) ? W_ih[g * 256 + k] : W_hh[g * 128 + (k - 256)];
    v[j] = (bf16_t)wv;
  }
  *(bf16x8*)(Wp_pk + ((size_t)blk * 64 + lane) * 8) = *(bf16x8*)v;
  if (kk == 0 && lane < 16) bp[r] = b_ih[g] + b_hh[g];
}

// ---- featproj: F[b][s][n] = bf16( exp( 2 * sum_t X[b][t][n] * W_x[s][t] ) ) ----
__global__ __launch_bounds__(256) void featproj_kernel(
    const float* __restrict__ X, const float* __restrict__ W_e, bf16_t* __restrict__ F) {
  int b  = blockIdx.x >> 2;
  int s0 = (blockIdx.x & 3) << 5;
  int tid = threadIdx.x;
  __shared__ float Xs[32][256];
  float acc[32];
#pragma unroll
  for (int i = 0; i < 32; ++i) acc[i] = 0.f;
  for (int tc = 0; tc < 4; ++tc) {
    __syncthreads();
#pragma unroll
    for (int i = 0; i < 32; ++i)
      Xs[i][tid] = X[((size_t)b * Tt + tc * 32 + i) * Nn + tid];
    __syncthreads();
    for (int tt = 0; tt < 32; ++tt) {
      float xv = Xs[tt][tid];
#pragma unroll
      for (int ss = 0; ss < 32; ++ss)
        acc[ss] = fmaf(W_e[(s0 + ss) * 384 + 256 + tc * 32 + tt], xv, acc[ss]);
    }
  }
#pragma unroll
  for (int ss = 0; ss < 32; ++ss)
    F[((size_t)b * 128 + s0 + ss) * 256 + tid] = (bf16_t)__expf(2.f * acc[ss]);
}

// ---- fused recurrence: 256 blocks x 512 threads, block owns 2 b's for all t ----
// Gate weights: 48 B-frags/lane (192 VGPRs) held in registers for ALL 128 steps.
__global__ __launch_bounds__(512, 2) void fused_kernel(
    const float* __restrict__ X, const bf16_t* __restrict__ F,
    const bf16_t* __restrict__ Whs_pk, const bf16_t* __restrict__ Wp_pk,
    const float* __restrict__ bp, const float* __restrict__ v_e,
    float* __restrict__ out) {
  __shared__ __align__(16) bf16_t WhsL[32768];     // 64 KB, loaded once
  __shared__ __align__(16) bf16_t hsA[16][264];    // A-frag [h|c] rows 0,1
  __shared__ __align__(16) bf16_t xtA[16][392];    // A-frag [x~|h] rows 0,1
  __shared__ float2 avL[2][128];                   // {exp(2a), -2v}
  __shared__ float  Ep[8][256];
  __shared__ float  gld[2][512];
  __shared__ float  hcC[2][128];                   // c state (f32)
  __shared__ float  vmL[128];
  __shared__ float  bpL[512];
  __shared__ float  red[8];

  int bid = blockIdx.x;
  int b0 = 2 * ((bid & 7) * 32 + (bid >> 3));      // XCD-contiguous b-ranges
  int tid = threadIdx.x;
  int w = tid >> 6, lane = tid & 63;
  int fr = lane & 15, ksel = lane >> 4;

  // one-time: persistent gate-weight fragments -> registers (192 VGPR/lane)
  bf16x8 wfr[4][12];
  {
    const bf16_t* wpw = Wp_pk + (size_t)(4 * w) * 6144 + (size_t)lane * 8;
#pragma unroll
    for (int j = 0; j < 4; ++j)
#pragma unroll
      for (int kk = 0; kk < 12; ++kk)
        wfr[j][kk] = *(const bf16x8*)(wpw + (size_t)j * 6144 + kk * 512);
  }
  // one-time init
  for (int i = tid; i < 4096; i += 512) ((uint4*)WhsL)[i] = ((const uint4*)Whs_pk)[i];
  for (int i = tid; i < 16 * 264; i += 512) ((bf16_t*)hsA)[i] = (bf16_t)0.f;
  for (int i = tid; i < 16 * 392; i += 512) ((bf16_t*)xtA)[i] = (bf16_t)0.f;
  if (tid < 128) { vmL[tid] = -2.f * v_e[tid]; hcC[0][tid] = 0.f; hcC[1][tid] = 0.f; }
  bpL[tid] = bp[tid];
  __syncthreads();

  for (int t = 0; t < Tt; ++t) {
    // ---- phase 1: a[b][s] = hs @ Whs^T (MFMA); av = {exp(2a), -2v} ----
    {
      f32x4 pa{};
#pragma unroll
      for (int kk = 0; kk < 8; ++kk) {
        bf16x8 af = *(const bf16x8*)&hsA[fr][kk * 32 + ksel * 8];
        bf16x8 bf = *(const bf16x8*)&WhsL[((w * 8 + kk) * 64 + lane) * 8];
        pa = __builtin_amdgcn_mfma_f32_16x16x32_bf16(af, bf, pa, 0, 0, 0);
      }
      if (ksel == 0) {                       // D rows 0,1 = batches b0,b0+1
        int s = w * 16 + fr;
        float vm = vmL[s];
        avL[0][s] = make_float2(__expf(2.f * pa[0]), vm);
        avL[1][s] = make_float2(__expf(2.f * pa[1]), vm);
      }
    }
    __syncthreads();

    // ---- phase 2: E partials. wave w: b = w>>2, s in [(w&3)*32, +32), n = 4*lane+j
    {
      int ab = w >> 2, s0 = (w & 3) * 32;
      const bf16_t* Fb = F + ((size_t)(b0 + ab) * 128 + s0) * 256 + 4 * lane;
      f32x4 En{};
#pragma unroll 8
      for (int s = 0; s < 32; ++s) {
        float2 avv = avL[ab][s0 + s];
        uint2 u = *(const uint2*)(Fb + (size_t)s * 256);
        float f0 = bflo(u.x), f1 = bfhi(u.x), f2 = bflo(u.y), f3 = bfhi(u.y);
        En[0] = fmaf(avv.y, __builtin_amdgcn_rcpf(fmaf(avv.x, f0, 1.f)), En[0]);
        En[1] = fmaf(avv.y, __builtin_amdgcn_rcpf(fmaf(avv.x, f1, 1.f)), En[1]);
        En[2] = fmaf(avv.y, __builtin_amdgcn_rcpf(fmaf(avv.x, f2, 1.f)), En[2]);
        En[3] = fmaf(avv.y, __builtin_amdgcn_rcpf(fmaf(avv.x, f3, 1.f)), En[3]);
      }
      *(f32x4*)&Ep[w][4 * lane] = En;
    }
    __syncthreads();

    // ---- phase 3: softmax over n (no max pass: |E| <= sum|v| ~ 5.2) + x_tilde
    {
      int sb = tid >> 8, sn = tid & 255;
      float E = Ep[sb * 4 + 0][sn] + Ep[sb * 4 + 1][sn] +
                Ep[sb * 4 + 2][sn] + Ep[sb * 4 + 3][sn];
      float p = __expf(E);
      float sm = p;
#pragma unroll
      for (int off = 32; off; off >>= 1) sm += __shfl_xor(sm, off, 64);
      if (lane == 0) red[tid >> 6] = sm;
      __syncthreads();
      sm = red[sb * 4 + 0] + red[sb * 4 + 1] + red[sb * 4 + 2] + red[sb * 4 + 3];
      float alpha = p * __builtin_amdgcn_rcpf(sm);
      float xv = X[((size_t)(b0 + sb) * Tt + t) * Nn + sn];
      xtA[sb][sn] = (bf16_t)(xv * alpha);
    }
    __syncthreads();

    // ---- phase 4: gates = [x~|h] @ Wp^T (MFMA, weights in regs) ----
    {
      f32x4 acg[4] = {f32x4{}, f32x4{}, f32x4{}, f32x4{}};
#pragma unroll
      for (int kk = 0; kk < 12; ++kk) {
        bf16x8 af = *(const bf16x8*)&xtA[fr][kk * 32 + ksel * 8];
#pragma unroll
        for (int j = 0; j < 4; ++j)
          acg[j] = __builtin_amdgcn_mfma_f32_16x16x32_bf16(af, wfr[j][kk], acg[j], 0, 0, 0);
      }
      if (ksel == 0) {
#pragma unroll
        for (int j = 0; j < 4; ++j) {
          gld[0][(4 * w + j) * 16 + fr] = acg[j][0];
          gld[1][(4 * w + j) * 16 + fr] = acg[j][1];
        }
      }
    }
    __syncthreads();

    // ---- phase 5: LSTM pointwise update (threads 0..255: ub = tid>>7, m = tid&127)
    if (tid < 256) {
      int ub = tid >> 7, m = tid & 127;
      int r = ((m >> 4) << 6) + (m & 15);
      float ig = fast_sigmoid(gld[ub][r]      + bpL[r]);
      float fg = fast_sigmoid(gld[ub][r + 16] + bpL[r + 16]);
      float gg = fast_tanh   (gld[ub][r + 32] + bpL[r + 32]);
      float og = fast_sigmoid(gld[ub][r + 48] + bpL[r + 48]);
      float c2 = fg * hcC[ub][m] + ig * gg;
      float h2 = og * fast_tanh(c2);
      hcC[ub][m] = c2;
      hsA[ub][m] = (bf16_t)h2;
      hsA[ub][128 + m] = (bf16_t)c2;
      xtA[ub][256 + m] = (bf16_t)h2;
      out[((size_t)t * Bb + (b0 + ub)) * Mm + m] = h2;
    }
    __syncthreads();
  }
}

extern "C" void kernel_launch(void* const* d_in, const int* in_sizes, int n_in,
                              void* d_out, int out_size, void* d_ws, size_t ws_size,
                              hipStream_t stream) {
  const float* X    = (const float*)d_in[0];
  const float* W_e  = (const float*)d_in[1];
  const float* v_e  = (const float*)d_in[2];
  const float* W_ih = (const float*)d_in[3];
  const float* W_hh = (const float*)d_in[4];
  const float* b_ih = (const float*)d_in[5];
  const float* b_hh = (const float*)d_in[6];
  float* out = (float*)d_out;

  char* ws = (char*)d_ws;
  bf16_t* F      = (bf16_t*)ws;                    // 512*128*256*2 = 33,554,432
  bf16_t* Whs_pk = (bf16_t*)(ws + 33554432);       // 65,536
  bf16_t* Wp_pk  = (bf16_t*)(ws + 33619968);       // 393,216
  float*  bp     = (float*) (ws + 34013184);       // 2,048

  prep_whs<<<64, 64, 0, stream>>>(W_e, Whs_pk);
  prep_wp<<<384, 64, 0, stream>>>(W_ih, W_hh, b_ih, b_hh, Wp_pk, bp);
  featproj_kernel<<<2048, 256, 0, stream>>>(X, W_e, F);
  fused_kernel<<<256, 512, 0, stream>>>(X, F, Whs_pk, Wp_pk, bp, v_e, out);
}

// Round 6
// 912.358 us; speedup vs baseline: 4.6455x; 1.6376x over previous
//
#include <hip/hip_runtime.h>
#include <hip/hip_bf16.h>

#define Bb 512
#define Tt 128
#define Nn 256
#define Mm 128

typedef __bf16 bf16_t;
typedef __bf16 bf16x8 __attribute__((ext_vector_type(8)));
typedef float f32x4 __attribute__((ext_vector_type(4)));
typedef unsigned u32x4 __attribute__((ext_vector_type(4)));

__device__ __forceinline__ float bflo(unsigned u) { return __uint_as_float(u << 16); }
__device__ __forceinline__ float bfhi(unsigned u) { return __uint_as_float(u & 0xffff0000u); }

__device__ __forceinline__ float fast_sigmoid(float x) {
  return __builtin_amdgcn_rcpf(1.f + __expf(-x));
}
__device__ __forceinline__ float fast_tanh(float x) {
  float e = __expf(2.f * x);
  return 1.f - 2.f * __builtin_amdgcn_rcpf(e + 1.f);
}

// ---- prep: Whs packed into MFMA B-frag order: [st(8)][kk(8)][lane(64)][8] ----
__global__ void prep_whs(const float* __restrict__ W_e, bf16_t* __restrict__ Whs_pk) {
  int blk = blockIdx.x;            // 0..63 = st*8 + kk
  int st = blk >> 3, kk = blk & 7;
  int lane = threadIdx.x;
  int s = st * 16 + (lane & 15);
  int m0 = kk * 32 + (lane >> 4) * 8;
  bf16_t v[8];
#pragma unroll
  for (int j = 0; j < 8; ++j) v[j] = (bf16_t)W_e[s * 384 + m0 + j];
  *(bf16x8*)(Whs_pk + ((size_t)blk * 64 + lane) * 8) = *(bf16x8*)v;
}

// ---- prep: Wp packed B-frags [gt(32)][kk(12)][lane(64)][8] + permuted bias ----
__global__ void prep_wp(const float* __restrict__ W_ih, const float* __restrict__ W_hh,
                        const float* __restrict__ b_ih, const float* __restrict__ b_hh,
                        bf16_t* __restrict__ Wp_pk, float* __restrict__ bp) {
  int blk = blockIdx.x;            // 0..383 = gt*12 + kk
  int gt = blk / 12, kk = blk % 12;
  int lane = threadIdx.x;
  int r = gt * 16 + (lane & 15);
  int mt = r >> 6, type = (r >> 4) & 3, ml = r & 15;
  int g = type * 128 + mt * 16 + ml;
  int k0 = kk * 32 + (lane >> 4) * 8;
  bf16_t v[8];
#pragma unroll
  for (int j = 0; j < 8; ++j) {
    int k = k0 + j;
    float wv = (k < 256) ? W_ih[g * 256 + k] : W_hh[g * 128 + (k - 256)];
    v[j] = (bf16_t)wv;
  }
  *(bf16x8*)(Wp_pk + ((size_t)blk * 64 + lane) * 8) = *(bf16x8*)v;
  if (kk == 0 && lane < 16) bp[r] = b_ih[g] + b_hh[g];
}

// ---- featproj: F[b][s][n] = bf16( exp( 2 * sum_t X[b][t][n] * W_x[s][t] ) ) ----
__global__ __launch_bounds__(256) void featproj_kernel(
    const float* __restrict__ X, const float* __restrict__ W_e, bf16_t* __restrict__ F) {
  int b  = blockIdx.x >> 2;
  int s0 = (blockIdx.x & 3) << 5;
  int tid = threadIdx.x;
  __shared__ float Xs[32][256];
  float acc[32];
#pragma unroll
  for (int i = 0; i < 32; ++i) acc[i] = 0.f;
  for (int tc = 0; tc < 4; ++tc) {
    __syncthreads();
#pragma unroll
    for (int i = 0; i < 32; ++i)
      Xs[i][tid] = X[((size_t)b * Tt + tc * 32 + i) * Nn + tid];
    __syncthreads();
    for (int tt = 0; tt < 32; ++tt) {
      float xv = Xs[tt][tid];
#pragma unroll
      for (int ss = 0; ss < 32; ++ss)
        acc[ss] = fmaf(W_e[(s0 + ss) * 384 + 256 + tc * 32 + tt], xv, acc[ss]);
    }
  }
#pragma unroll
  for (int ss = 0; ss < 32; ++ss)
    F[((size_t)b * 128 + s0 + ss) * 256 + tid] = (bf16_t)__expf(2.f * acc[ss]);
}

#define BCAST(x) __builtin_bit_cast(bf16x8, x)

// ---- fused recurrence: 256 blocks x 512 threads; all weights pinned in VGPRs;
// F resident in LDS; zero steady-state global reads except X row.
__global__ __launch_bounds__(512, 2) void fused_kernel(
    const float* __restrict__ X, const bf16_t* __restrict__ F,
    const bf16_t* __restrict__ Whs_pk, const bf16_t* __restrict__ Wp_pk,
    const float* __restrict__ bp, const float* __restrict__ v_e,
    float* __restrict__ out) {
  __shared__ __align__(16) bf16_t Fl[2][128][256];   // 131072 B, filled once
  __shared__ __align__(16) bf16_t Abuf[16][520];     // [x~ 0..255 | h 256..383 | c 384..511]
  __shared__ float2 avL[2][128];                     // {exp(2a), -2v}
  __shared__ float  Ep[8][256];                      // E partials

  int bid = blockIdx.x;
  int b0 = 2 * ((bid & 7) * 32 + (bid >> 3));        // XCD-contiguous b-ranges
  int tid = threadIdx.x;
  int w = tid >> 6, lane = tid & 63;
  int fr = lane & 15, ksel = lane >> 4;

  // ---- pinned weight fragments (anti-remat via volatile asm touch) ----
  u32x4 wq[48];  // gates: wave w owns g-tiles 4w..4w+3, 12 kk each = 192 VGPR
  u32x4 hq[8];   // Whs: wave w owns s-tile w, 8 kk = 32 VGPR
  {
    const u32x4* wp4 = (const u32x4*)Wp_pk;
#pragma unroll
    for (int j = 0; j < 4; ++j)
#pragma unroll
      for (int kk = 0; kk < 12; ++kk)
        wq[j * 12 + kk] = wp4[(size_t)((4 * w + j) * 12 + kk) * 64 + lane];
    const u32x4* wh4 = (const u32x4*)Whs_pk;
#pragma unroll
    for (int kk = 0; kk < 8; ++kk)
      hq[kk] = wh4[(size_t)(w * 8 + kk) * 64 + lane];
#pragma unroll
    for (int i = 0; i < 48; ++i) asm volatile("" : "+v"(wq[i]));
#pragma unroll
    for (int i = 0; i < 8; ++i) asm volatile("" : "+v"(hq[i]));
  }
  // per-lane constants
  float biasr[4];
#pragma unroll
  for (int j = 0; j < 4; ++j) biasr[j] = bp[(4 * w + j) * 16 + fr];
  float vmr = -2.f * v_e[w * 16 + fr];
  float c0r = 0.f, c1r = 0.f;

  // one-time LDS fill
  {
    const u32x4* src = (const u32x4*)(F + (size_t)b0 * 32768);
    u32x4* dst = (u32x4*)&Fl[0][0][0];
    for (int i = tid; i < 8192; i += 512) dst[i] = src[i];
    u32x4 z = {0, 0, 0, 0};
    u32x4* ab = (u32x4*)&Abuf[0][0];
    for (int i = tid; i < 1040; i += 512) ab[i] = z;
  }
  __syncthreads();

  for (int t = 0; t < Tt; ++t) {
    // X prefetch for phase 3 (waves 0,1 only); completes by barrier A
    float4 xpre = make_float4(0.f, 0.f, 0.f, 0.f);
    if (w < 2)
      xpre = *(const float4*)(X + ((size_t)(b0 + w) * Tt + t) * Nn + 4 * lane);

    // ---- phase 1: a = [h|c] @ Whs^T (MFMA, weights in regs) ----
    {
      f32x4 pa = {0.f, 0.f, 0.f, 0.f};
#pragma unroll
      for (int kk = 0; kk < 8; ++kk) {
        bf16x8 af = *(const bf16x8*)&Abuf[fr][256 + kk * 32 + ksel * 8];
        pa = __builtin_amdgcn_mfma_f32_16x16x32_bf16(af, BCAST(hq[kk]), pa, 0, 0, 0);
      }
      if (ksel == 0) {
        int s = w * 16 + fr;
        avL[0][s] = make_float2(__expf(2.f * pa[0]), vmr);
        avL[1][s] = make_float2(__expf(2.f * pa[1]), vmr);
      }
    }
    __syncthreads();  // A: avL ready

    // ---- phase 2: E partials (wave w: batch w>>2, s in [(w&3)*32,+32), n=4*lane+j)
    {
      int ab = w >> 2, sq = (w & 3) * 32;
      const bf16_t* frow = &Fl[ab][sq][4 * lane];
      f32x4 En = {0.f, 0.f, 0.f, 0.f};
#pragma unroll 8
      for (int s = 0; s < 32; ++s) {
        float2 avv = avL[ab][sq + s];
        uint2 u = *(const uint2*)(frow + s * 256);
        En[0] = fmaf(avv.y, __builtin_amdgcn_rcpf(fmaf(avv.x, bflo(u.x), 1.f)), En[0]);
        En[1] = fmaf(avv.y, __builtin_amdgcn_rcpf(fmaf(avv.x, bfhi(u.x), 1.f)), En[1]);
        En[2] = fmaf(avv.y, __builtin_amdgcn_rcpf(fmaf(avv.x, bflo(u.y), 1.f)), En[2]);
        En[3] = fmaf(avv.y, __builtin_amdgcn_rcpf(fmaf(avv.x, bfhi(u.y), 1.f)), En[3]);
      }
      *(f32x4*)&Ep[w][4 * lane] = En;
    }
    __syncthreads();  // B: Ep ready

    // ---- phase 3: softmax (no max pass: |E| <= sum|v| ~ 5) + x_tilde.
    // One wave per batch holds all 256 n (4 per lane) -> intra-wave reduce only.
    if (w < 2) {
      int n0 = 4 * lane;
      f32x4 E  = *(const f32x4*)&Ep[w * 4 + 0][n0];
      f32x4 e1 = *(const f32x4*)&Ep[w * 4 + 1][n0];
      f32x4 e2 = *(const f32x4*)&Ep[w * 4 + 2][n0];
      f32x4 e3 = *(const f32x4*)&Ep[w * 4 + 3][n0];
      E = E + e1 + e2 + e3;
      float p0 = __expf(E[0]), p1 = __expf(E[1]), p2 = __expf(E[2]), p3 = __expf(E[3]);
      float tot = (p0 + p1) + (p2 + p3);
#pragma unroll
      for (int off = 32; off; off >>= 1) tot += __shfl_xor(tot, off, 64);
      float ir = __builtin_amdgcn_rcpf(tot);
      bf16_t xb[4];
      xb[0] = (bf16_t)(xpre.x * (p0 * ir));
      xb[1] = (bf16_t)(xpre.y * (p1 * ir));
      xb[2] = (bf16_t)(xpre.z * (p2 * ir));
      xb[3] = (bf16_t)(xpre.w * (p3 * ir));
      *(uint2*)&Abuf[w][n0] = *(uint2*)xb;
    }
    __syncthreads();  // D: x_tilde ready

    // ---- phase 4: gates = [x~|h] @ Wp^T (MFMA, weights in regs) + in-reg LSTM ----
    float h0w = 0.f, c0w = 0.f, h1w = 0.f, c1w = 0.f;
    {
      f32x4 acg0 = {0,0,0,0}, acg1 = {0,0,0,0}, acg2 = {0,0,0,0}, acg3 = {0,0,0,0};
#pragma unroll
      for (int kk = 0; kk < 12; ++kk) {
        bf16x8 af = *(const bf16x8*)&Abuf[fr][kk * 32 + ksel * 8];
        acg0 = __builtin_amdgcn_mfma_f32_16x16x32_bf16(af, BCAST(wq[0 * 12 + kk]), acg0, 0, 0, 0);
        acg1 = __builtin_amdgcn_mfma_f32_16x16x32_bf16(af, BCAST(wq[1 * 12 + kk]), acg1, 0, 0, 0);
        acg2 = __builtin_amdgcn_mfma_f32_16x16x32_bf16(af, BCAST(wq[2 * 12 + kk]), acg2, 0, 0, 0);
        acg3 = __builtin_amdgcn_mfma_f32_16x16x32_bf16(af, BCAST(wq[3 * 12 + kk]), acg3, 0, 0, 0);
      }
      // D layout: col = lane&15 (= m-local), row = ksel*4 + reg (= batch 0/1 at ksel==0)
      if (ksel == 0) {
        int m = w * 16 + fr;
        {
          float ig = fast_sigmoid(acg0[0] + biasr[0]);
          float fg = fast_sigmoid(acg1[0] + biasr[1]);
          float gg = fast_tanh   (acg2[0] + biasr[2]);
          float og = fast_sigmoid(acg3[0] + biasr[3]);
          c0w = fg * c0r + ig * gg;  h0w = og * fast_tanh(c0w);  c0r = c0w;
        }
        {
          float ig = fast_sigmoid(acg0[1] + biasr[0]);
          float fg = fast_sigmoid(acg1[1] + biasr[1]);
          float gg = fast_tanh   (acg2[1] + biasr[2]);
          float og = fast_sigmoid(acg3[1] + biasr[3]);
          c1w = fg * c1r + ig * gg;  h1w = og * fast_tanh(c1w);  c1r = c1w;
        }
        out[((size_t)t * Bb + b0) * Mm + m]     = h0w;
        out[((size_t)t * Bb + b0 + 1) * Mm + m] = h1w;
      }
    }
    __syncthreads();  // E1: all phase-4 LDS reads complete before h/c overwrite
    if (ksel == 0) {
      int m = w * 16 + fr;
      Abuf[0][256 + m] = (bf16_t)h0w;
      Abuf[0][384 + m] = (bf16_t)c0w;
      Abuf[1][256 + m] = (bf16_t)h1w;
      Abuf[1][384 + m] = (bf16_t)c1w;
    }
    __syncthreads();  // E2: new h/c visible for next step
  }
}

extern "C" void kernel_launch(void* const* d_in, const int* in_sizes, int n_in,
                              void* d_out, int out_size, void* d_ws, size_t ws_size,
                              hipStream_t stream) {
  const float* X    = (const float*)d_in[0];
  const float* W_e  = (const float*)d_in[1];
  const float* v_e  = (const float*)d_in[2];
  const float* W_ih = (const float*)d_in[3];
  const float* W_hh = (const float*)d_in[4];
  const float* b_ih = (const float*)d_in[5];
  const float* b_hh = (const float*)d_in[6];
  float* out = (float*)d_out;

  char* ws = (char*)d_ws;
  bf16_t* F      = (bf16_t*)ws;                    // 33,554,432
  bf16_t* Whs_pk = (bf16_t*)(ws + 33554432);       // 65,536
  bf16_t* Wp_pk  = (bf16_t*)(ws + 33619968);       // 393,216
  float*  bp     = (float*) (ws + 34013184);       // 2,048

  prep_whs<<<64, 64, 0, stream>>>(W_e, Whs_pk);
  prep_wp<<<384, 64, 0, stream>>>(W_ih, W_hh, b_ih, b_hh, Wp_pk, bp);
  featproj_kernel<<<2048, 256, 0, stream>>>(X, W_e, F);
  fused_kernel<<<256, 512, 0, stream>>>(X, F, Whs_pk, Wp_pk, bp, v_e, out);
}